// Round 8
// baseline (11.498 us; speedup 1.0000x reference)
//
#include <hip/hip_runtime.h>

#define DIMS 64
#define KF 16
#define F 128   // 2*DIMS
#define ROWS 8              // rows per wave (two groups of 4)
#define ROWS_PER_BLOCK 32   // 4 waves x ROWS

// DPP lane permute: pure VALU, no LDS pipe, no waitcnt.
template<int CTRL>
__device__ __forceinline__ float dppmv(float x) {
    return __builtin_bit_cast(float,
        __builtin_amdgcn_update_dpp(0, __builtin_bit_cast(int, x), CTRL, 0xF, 0xF, true));
}
// Single-instruction LDS-crossbar swizzle.
template<int PAT>
__device__ __forceinline__ float swzf(float x) {
    return __builtin_bit_cast(float,
        __builtin_amdgcn_ds_swizzle(__builtin_bit_cast(int, x), PAT));
}

#define DPP_XOR1  0xB1   // quad_perm(1,0,3,2)
#define DPP_XOR2  0x4E   // quad_perm(2,3,0,1)
#define DPP_XOR8  0x128  // row_ror:8 (== xor 8 within 16)
#define SWZ_XOR4  0x101F // BitMode xor_mask=4
#define SWZ_XOR16 0x401F // BitMode xor_mask=16

__device__ __forceinline__ float sum_xor16(float x) {
#if __has_builtin(__builtin_amdgcn_permlane16_swap)
    auto r = __builtin_amdgcn_permlane16_swap(__builtin_bit_cast(int, x),
                                              __builtin_bit_cast(int, x), false, false);
    return __builtin_bit_cast(float, (int)r[0]) + __builtin_bit_cast(float, (int)r[1]);
#else
    return x + swzf<SWZ_XOR16>(x);
#endif
}
__device__ __forceinline__ float sum_xor32(float x) {
#if __has_builtin(__builtin_amdgcn_permlane32_swap)
    auto r = __builtin_amdgcn_permlane32_swap(__builtin_bit_cast(int, x),
                                              __builtin_bit_cast(int, x), false, false);
    return __builtin_bit_cast(float, (int)r[0]) + __builtin_bit_cast(float, (int)r[1]);
#else
    return x + __shfl_xor(x, 32, 64);
#endif
}

__global__ __launch_bounds__(256, 4) void fm_fwd_kernel(
    const int* __restrict__ user,
    const int* __restrict__ item,
    const float* __restrict__ user_emb,
    const float* __restrict__ item_emb,
    const float* __restrict__ w1,
    const float* __restrict__ b1,
    const float* __restrict__ v,
    float* __restrict__ out,
    int B)
{
    __shared__ float vsT[KF * F];   // vsT[k*F + f] = v[f][k]; 8 KB

    const int tid  = threadIdx.x;
    const int lane = tid & 63;
    const int wv   = tid >> 6;
    const int q    = lane & 31;     // feature-pair index within half
    const int half = lane >> 5;     // 0 = user half, 1 = item half

    // ---- 1. v staging loads FIRST (oldest vmem: ds_writes wait at vmcnt(N),
    //         leaving all row gathers in flight) ----
    const float4* vg = (const float4*)v;
    const float4 p0 = vg[tid * 2 + 0];
    const float4 p1 = vg[tid * 2 + 1];

    // ---- 2. indices: two s_load_dwordx4 per table on the fast path ----
    const int base = __builtin_amdgcn_readfirstlane(
        (int)blockIdx.x * ROWS_PER_BLOCK + wv * ROWS);
    int ui[ROWS], ti[ROWS];
    if ((int)(blockIdx.x + 1) * ROWS_PER_BLOCK <= B) {
        const int4 u0 = *(const int4*)(user + base);
        const int4 u1 = *(const int4*)(user + base + 4);
        const int4 t0 = *(const int4*)(item + base);
        const int4 t1 = *(const int4*)(item + base + 4);
        ui[0]=u0.x; ui[1]=u0.y; ui[2]=u0.z; ui[3]=u0.w;
        ui[4]=u1.x; ui[5]=u1.y; ui[6]=u1.z; ui[7]=u1.w;
        ti[0]=t0.x; ti[1]=t0.y; ti[2]=t0.z; ti[3]=t0.w;
        ti[4]=t1.x; ti[5]=t1.y; ti[6]=t1.z; ti[7]=t1.w;
    } else {
        #pragma unroll
        for (int r = 0; r < ROWS; ++r) {
            const int i = min(base + r, B - 1);
            ui[r] = user[i];
            ti[r] = item[i];
        }
    }

    // ---- 3. paired gathers: one instruction per row; all 8 issued upfront.
    //         Group-B gathers remain in flight during group-A compute. ----
    float2 x[ROWS];
    #pragma unroll
    for (int r = 0; r < ROWS; ++r) {
        const float* src = half ? (item_emb + (size_t)ti[r] * DIMS)
                                : (user_emb + (size_t)ui[r] * DIMS);
        x[r] = *(const float2*)(src + 2 * q);
    }

    const float2 w2 = *(const float2*)(w1 + half * DIMS + 2 * q);
    const float bias = b1[0];

    // ---- 4. stage v transposed into LDS ----
    {
        const int f  = tid >> 1;
        const int k0 = (tid & 1) * 8;
        vsT[(k0+0)*F + f] = p0.x;  vsT[(k0+1)*F + f] = p0.y;
        vsT[(k0+2)*F + f] = p0.z;  vsT[(k0+3)*F + f] = p0.w;
        vsT[(k0+4)*F + f] = p1.x;  vsT[(k0+5)*F + f] = p1.y;
        vsT[(k0+6)*F + f] = p1.z;  vsT[(k0+7)*F + f] = p1.w;
    }
    asm volatile("s_waitcnt lgkmcnt(0)" ::: "memory");
    __builtin_amdgcn_s_barrier();

    const float2* vs2 = ((const float2*)vsT) + lane;

    float rrA, rrB;       // per-group folded results
    float A0 = 0.f, A1 = 0.f;

    #define HALVE2(SA, SB, MV, M, N) { \
        const bool hi = (lane & (M)) != 0; \
        _Pragma("unroll") \
        for (int i = 0; i < (N); ++i) { \
            float kA = hi ? SA[(N)+i] : SA[i]; float dA = hi ? SA[i] : SA[(N)+i]; \
            float kB = hi ? SB[(N)+i] : SB[i]; float dB = hi ? SB[i] : SB[(N)+i]; \
            SA[i] = kA + MV(dA); \
            SB[i] = kB + MV(dB); \
        } }
    #define REDUCE_PAIR(SA, SB, CA, CB) { \
        HALVE2(SA, SB, dppmv<DPP_XOR1>, 1, 8) \
        HALVE2(SA, SB, dppmv<DPP_XOR2>, 2, 4) \
        HALVE2(SA, SB, dppmv<DPP_XOR8>, 8, 2) \
        HALVE2(SA, SB, swzf<SWZ_XOR4>,  4, 1) \
        float svA = sum_xor32(sum_xor16(SA[0])); \
        float svB = sum_xor32(sum_xor16(SB[0])); \
        CA += 0.125f * svA * svA; \
        CB += 0.125f * svB * svB; \
    }

    #pragma unroll
    for (int g = 0; g < 2; ++g) {
        const int o = g * 4;
        // k-loop: one conflict-free ds_read_b64 per k feeds 4 rows.
        float s0[KF], s1[KF], s2[KF], s3[KF];
        #pragma unroll
        for (int k = 0; k < KF; ++k) {
            const float2 vv = vs2[k * 64];
            if (g == 0) {           // A0/A1 computed once, reused for group B
                A0 += vv.x * vv.x;
                A1 += vv.y * vv.y;
            }
            s0[k] = x[o+0].x * vv.x + x[o+0].y * vv.y;
            s1[k] = x[o+1].x * vv.x + x[o+1].y * vv.y;
            s2[k] = x[o+2].x * vv.x + x[o+2].y * vv.y;
            s3[k] = x[o+3].x * vv.x + x[o+3].y * vv.y;
        }
        float c[4];
        #pragma unroll
        for (int r = 0; r < 4; ++r)
            c[r] = x[o+r].x * w2.x + x[o+r].y * w2.y
                 - 0.5f * (x[o+r].x * x[o+r].x * A0 + x[o+r].y * x[o+r].y * A1);

        REDUCE_PAIR(s0, s1, c[0], c[1])
        REDUCE_PAIR(s2, s3, c[2], c[3])

        // Cross-row fold: 4 rows -> one value per lane-coset.
        float r0, r1;
        {
            const bool hi = (lane & 1) != 0;
            float k0 = hi ? c[2] : c[0], d0 = hi ? c[0] : c[2];
            float k1 = hi ? c[3] : c[1], d1 = hi ? c[1] : c[3];
            r0 = k0 + dppmv<DPP_XOR1>(d0);
            r1 = k1 + dppmv<DPP_XOR1>(d1);
        }
        float rr;
        {
            const bool hi = (lane & 2) != 0;
            float kk = hi ? r1 : r0, dd = hi ? r0 : r1;
            rr = kk + dppmv<DPP_XOR2>(dd);
        }
        rr += swzf<SWZ_XOR4>(rr);
        rr += dppmv<DPP_XOR8>(rr);
        rr = sum_xor16(rr);
        rr = sum_xor32(rr);
        if (g == 0) rrA = rr; else rrB = rr;
    }
    #undef REDUCE_PAIR
    #undef HALVE2

    // After the butterfly every lane holds its coset's total: lane c -> row
    // ((c&1)<<1)|((c>>1)&1). Lanes 0-3 write group A, lanes 4-7 group B.
    if (lane < 8) {
        const int rloc = ((lane & 1) << 1) | ((lane >> 1) & 1);
        const int row  = base + (lane >> 2) * 4 + rloc;
        const float val = (lane < 4) ? rrA : rrB;
        if (row < B)
            out[row] = bias + val;
    }
}

extern "C" void kernel_launch(void* const* d_in, const int* in_sizes, int n_in,
                              void* d_out, int out_size, void* d_ws, size_t ws_size,
                              hipStream_t stream) {
    const int*   user     = (const int*)  d_in[0];
    const int*   item     = (const int*)  d_in[1];
    const float* user_emb = (const float*)d_in[2];
    const float* item_emb = (const float*)d_in[3];
    const float* w1       = (const float*)d_in[4];
    const float* b1       = (const float*)d_in[5];
    const float* v        = (const float*)d_in[6];
    float* out = (float*)d_out;

    const int B = in_sizes[0];
    const int blocks = (B + ROWS_PER_BLOCK - 1) / ROWS_PER_BLOCK;
    fm_fwd_kernel<<<blocks, 256, 0, stream>>>(user, item, user_emb, item_emb,
                                              w1, b1, v, out, B);
}

// Round 9
// 9.742 us; speedup vs baseline: 1.1802x; 1.1802x over previous
//
#include <hip/hip_runtime.h>

#define DIMS 64
#define KF 16
#define F 128   // 2*DIMS
#define ROWS 4
#define ROWS_PER_BLOCK 16   // 4 waves x ROWS

// DPP lane permute: pure VALU, no LDS pipe, no waitcnt.
template<int CTRL>
__device__ __forceinline__ float dppmv(float x) {
    return __builtin_bit_cast(float,
        __builtin_amdgcn_update_dpp(0, __builtin_bit_cast(int, x), CTRL, 0xF, 0xF, true));
}
// Single-instruction LDS-crossbar swizzle.
template<int PAT>
__device__ __forceinline__ float swzf(float x) {
    return __builtin_bit_cast(float,
        __builtin_amdgcn_ds_swizzle(__builtin_bit_cast(int, x), PAT));
}

#define DPP_XOR1  0xB1   // quad_perm(1,0,3,2)
#define DPP_XOR2  0x4E   // quad_perm(2,3,0,1)
#define DPP_XOR8  0x128  // row_ror:8 (== xor 8 within 16)
#define SWZ_XOR4  0x101F // BitMode xor_mask=4
#define SWZ_XOR16 0x401F // BitMode xor_mask=16

// y[l] = x[l] + x[l^16], pure VALU on gfx950.
__device__ __forceinline__ float sum_xor16(float x) {
#if __has_builtin(__builtin_amdgcn_permlane16_swap)
    auto r = __builtin_amdgcn_permlane16_swap(__builtin_bit_cast(int, x),
                                              __builtin_bit_cast(int, x), false, false);
    return __builtin_bit_cast(float, (int)r[0]) + __builtin_bit_cast(float, (int)r[1]);
#else
    return x + swzf<SWZ_XOR16>(x);
#endif
}
// y[l] = x[l] + x[l^32], pure VALU on gfx950.
__device__ __forceinline__ float sum_xor32(float x) {
#if __has_builtin(__builtin_amdgcn_permlane32_swap)
    auto r = __builtin_amdgcn_permlane32_swap(__builtin_bit_cast(int, x),
                                              __builtin_bit_cast(int, x), false, false);
    return __builtin_bit_cast(float, (int)r[0]) + __builtin_bit_cast(float, (int)r[1]);
#else
    return x + __shfl_xor(x, 32, 64);
#endif
}

__global__ __launch_bounds__(256, 4) void fm_fwd_kernel(
    const int* __restrict__ user,
    const int* __restrict__ item,
    const float* __restrict__ user_emb,
    const float* __restrict__ item_emb,
    const float* __restrict__ w1,
    const float* __restrict__ b1,
    const float* __restrict__ v,
    float* __restrict__ out,
    int B)
{
    __shared__ float vsT[KF * F];   // vsT[k*F + f] = v[f][k]; 8 KB

    const int tid  = threadIdx.x;
    const int lane = tid & 63;
    const int wv   = tid >> 6;
    const int q    = lane & 31;     // feature pair index within half
    const int half = lane >> 5;     // 0 = user half, 1 = item half

    // ---- 1. v staging loads FIRST: oldest vmem, so the ds_writes below
    //         wait at vmcnt(N) and leave the row gathers in flight. ----
    const float4* vg = (const float4*)v;
    const float4 p0 = vg[tid * 2 + 0];
    const float4 p1 = vg[tid * 2 + 1];

    // ---- 2. indices: one s_load_dwordx4 per table on the fast path ----
    const int base = __builtin_amdgcn_readfirstlane(
        (int)blockIdx.x * ROWS_PER_BLOCK + wv * ROWS);
    int ui[ROWS], ti[ROWS];
    if ((int)(blockIdx.x + 1) * ROWS_PER_BLOCK <= B) {
        const int4 uu = *(const int4*)(user + base);
        const int4 tt = *(const int4*)(item + base);
        ui[0] = uu.x; ui[1] = uu.y; ui[2] = uu.z; ui[3] = uu.w;
        ti[0] = tt.x; ti[1] = tt.y; ti[2] = tt.z; ti[3] = tt.w;
    } else {
        #pragma unroll
        for (int r = 0; r < ROWS; ++r) {
            const int i = min(base + r, B - 1);
            ui[r] = user[i];
            ti[r] = item[i];
        }
    }

    // ---- 3. paired gathers: ONE instruction per row. Lanes 0-31 fetch the
    //         user half (float2 each), lanes 32-63 the item half. ----
    float2 x[ROWS];
    #pragma unroll
    for (int r = 0; r < ROWS; ++r) {
        const float* src = half ? (item_emb + (size_t)ti[r] * DIMS)
                                : (user_emb + (size_t)ui[r] * DIMS);
        x[r] = *(const float2*)(src + 2 * q);
    }

    // ---- 4. w1 (one float2 per lane) + bias ----
    const float2 w2 = *(const float2*)(w1 + half * DIMS + 2 * q);
    const float bias = b1[0];

    // ---- 5. stage v transposed into LDS (consumes only p0/p1 -> vmcnt
    //         leaves gathers outstanding) ----
    {
        const int f  = tid >> 1;
        const int k0 = (tid & 1) * 8;
        vsT[(k0+0)*F + f] = p0.x;  vsT[(k0+1)*F + f] = p0.y;
        vsT[(k0+2)*F + f] = p0.z;  vsT[(k0+3)*F + f] = p0.w;
        vsT[(k0+4)*F + f] = p1.x;  vsT[(k0+5)*F + f] = p1.y;
        vsT[(k0+6)*F + f] = p1.z;  vsT[(k0+7)*F + f] = p1.w;
    }
    // LDS-only barrier: no vmem drain of the row gathers.
    asm volatile("s_waitcnt lgkmcnt(0)" ::: "memory");
    __builtin_amdgcn_s_barrier();

    // ---- 6. k-loop: lane reads its feature pair (f, f+1) for each k via a
    //         single conflict-free ds_read_b64; feeds all 4 rows. ----
    // float2 element index: (k*F + half*DIMS + 2q)/2 = k*64 + lane.
    const float2* vs2 = ((const float2*)vsT) + lane;
    float s0[KF], s1[KF], s2[KF], s3[KF];
    float A0 = 0.f, A1 = 0.f;   // sum_k v_{f,k}^2 , v_{f+1,k}^2 (per-lane)
    #pragma unroll
    for (int k = 0; k < KF; ++k) {
        const float2 vv = vs2[k * 64];
        A0 += vv.x * vv.x;
        A1 += vv.y * vv.y;
        s0[k] = x[0].x * vv.x + x[0].y * vv.y;
        s1[k] = x[1].x * vv.x + x[1].y * vv.y;
        s2[k] = x[2].x * vv.x + x[2].y * vv.y;
        s3[k] = x[3].x * vv.x + x[3].y * vv.y;
    }
    float c[ROWS];
    #pragma unroll
    for (int r = 0; r < ROWS; ++r)
        c[r] = x[r].x * w2.x + x[r].y * w2.y
             - 0.5f * (x[r].x * x[r].x * A0 + x[r].y * x[r].y * A1);

    // ---- 7. reductions (lane->k bijection permutation irrelevant since we
    //         sum S_k^2 over all k) ----
    #define HALVE2(SA, SB, MV, M, N) { \
        const bool hi = (lane & (M)) != 0; \
        _Pragma("unroll") \
        for (int i = 0; i < (N); ++i) { \
            float kA = hi ? SA[(N)+i] : SA[i]; float dA = hi ? SA[i] : SA[(N)+i]; \
            float kB = hi ? SB[(N)+i] : SB[i]; float dB = hi ? SB[i] : SB[(N)+i]; \
            SA[i] = kA + MV(dA); \
            SB[i] = kB + MV(dB); \
        } }
    #define REDUCE_PAIR(SA, SB, CA, CB) { \
        HALVE2(SA, SB, dppmv<DPP_XOR1>, 1, 8) \
        HALVE2(SA, SB, dppmv<DPP_XOR2>, 2, 4) \
        HALVE2(SA, SB, dppmv<DPP_XOR8>, 8, 2) \
        HALVE2(SA, SB, swzf<SWZ_XOR4>,  4, 1) \
        float svA = sum_xor32(sum_xor16(SA[0])); \
        float svB = sum_xor32(sum_xor16(SB[0])); \
        CA += 0.125f * svA * svA; \
        CB += 0.125f * svB * svB; \
    }
    REDUCE_PAIR(s0, s1, c[0], c[1])
    REDUCE_PAIR(s2, s3, c[2], c[3])
    #undef REDUCE_PAIR
    #undef HALVE2

    // Cross-row combine: fold 4 rows into one value per lane-coset, then one
    // shared butterfly finishes all rows.
    float r0, r1;
    {
        const bool hi = (lane & 1) != 0;
        float k0 = hi ? c[2] : c[0], d0 = hi ? c[0] : c[2];
        float k1 = hi ? c[3] : c[1], d1 = hi ? c[1] : c[3];
        r0 = k0 + dppmv<DPP_XOR1>(d0);
        r1 = k1 + dppmv<DPP_XOR1>(d1);
    }
    float rr;
    {
        const bool hi = (lane & 2) != 0;
        float kk = hi ? r1 : r0, dd = hi ? r0 : r1;
        rr = kk + dppmv<DPP_XOR2>(dd);
    }
    rr += swzf<SWZ_XOR4>(rr);
    rr += dppmv<DPP_XOR8>(rr);
    rr = sum_xor16(rr);
    rr = sum_xor32(rr);

    if (lane < ROWS) {
        const int row = ((lane & 1) << 1) | ((lane >> 1) & 1);
        if (base + row < B)
            out[base + row] = bias + rr;
    }
}

extern "C" void kernel_launch(void* const* d_in, const int* in_sizes, int n_in,
                              void* d_out, int out_size, void* d_ws, size_t ws_size,
                              hipStream_t stream) {
    const int*   user     = (const int*)  d_in[0];
    const int*   item     = (const int*)  d_in[1];
    const float* user_emb = (const float*)d_in[2];
    const float* item_emb = (const float*)d_in[3];
    const float* w1       = (const float*)d_in[4];
    const float* b1       = (const float*)d_in[5];
    const float* v        = (const float*)d_in[6];
    float* out = (float*)d_out;

    const int B = in_sizes[0];
    const int blocks = (B + ROWS_PER_BLOCK - 1) / ROWS_PER_BLOCK;
    fm_fwd_kernel<<<blocks, 256, 0, stream>>>(user, item, user_emb, item_emb,
                                              w1, b1, v, out, B);
}